// Round 4
// baseline (799.458 us; speedup 1.0000x reference)
//
#include <hip/hip_runtime.h>
#include <hip/hip_bf16.h>
#include <stdint.h>

typedef unsigned short u16;
typedef __attribute__((ext_vector_type(8))) short short8;
typedef __attribute__((ext_vector_type(4))) float f32x4;

#define T_TOK 2048
#define H_DIM 1024
#define E_NUM 16
#define TWO_I 2048
#define I_DIM 1024
#define ALPHA 1.702f
#define LIMIT 7.0f

__device__ __forceinline__ u16 f2b(float f) {
    uint32_t x = __builtin_bit_cast(uint32_t, f);
    uint32_t r = x + 0x7fffu + ((x >> 16) & 1u);
    return (u16)(r >> 16);
}
__device__ __forceinline__ short8 pack8(float4 a, float4 b) {
    short8 r;
    r[0] = (short)f2b(a.x); r[1] = (short)f2b(a.y);
    r[2] = (short)f2b(a.z); r[3] = (short)f2b(a.w);
    r[4] = (short)f2b(b.x); r[5] = (short)f2b(b.y);
    r[6] = (short)f2b(b.z); r[7] = (short)f2b(b.w);
    return r;
}

// ---------------------------------------------------------------------------
// Kernel 1: RMSNorm + gate + top-4 + softmax + expert scatter. 1 block/token.
// All math fp32 from fp32 inputs (must match np top-k ranking).
// ---------------------------------------------------------------------------
__global__ __launch_bounds__(256) void prep_kernel(
    const float* __restrict__ x, const float* __restrict__ scale,
    const float* __restrict__ gw, const float* __restrict__ gb,
    u16* __restrict__ t_out, int* __restrict__ cnt,
    int* __restrict__ pairs, float* __restrict__ pweight)
{
    const int t = blockIdx.x, tid = threadIdx.x;
    const int lane = tid & 63, wid = tid >> 6;
    __shared__ float red[4];
    __shared__ float g4[4][16];
    __shared__ float gsh[16];
    __shared__ float rstd_sh;

    const float4 xv = ((const float4*)(x + (size_t)t * H_DIM))[tid];
    float ss = xv.x*xv.x + xv.y*xv.y + xv.z*xv.z + xv.w*xv.w;
#pragma unroll
    for (int off = 32; off > 0; off >>= 1) ss += __shfl_down(ss, off);
    if (lane == 0) red[wid] = ss;
    __syncthreads();
    if (tid == 0) rstd_sh = rsqrtf((red[0]+red[1]+red[2]+red[3]) * (1.f/1024.f) + 1e-5f);
    __syncthreads();
    const float rstd = rstd_sh;
    const float4 sc = ((const float4*)scale)[tid];
    float4 tv;
    tv.x = xv.x * rstd * sc.x; tv.y = xv.y * rstd * sc.y;
    tv.z = xv.z * rstd * sc.z; tv.w = xv.w * rstd * sc.w;
    // store t as bf16 (8B packed store)
    {
        uint32_t lo = (uint32_t)f2b(tv.x) | ((uint32_t)f2b(tv.y) << 16);
        uint32_t hi = (uint32_t)f2b(tv.z) | ((uint32_t)f2b(tv.w) << 16);
        uint2 p; p.x = lo; p.y = hi;
        *(uint2*)(t_out + (size_t)t * H_DIM + tid * 4) = p;
    }
    // gate logits in fp32
    float part[16];
#pragma unroll
    for (int e = 0; e < 16; e++) {
        const float4 w4 = ((const float4*)(gw + (size_t)e * H_DIM))[tid];
        part[e] = tv.x*w4.x + tv.y*w4.y + tv.z*w4.z + tv.w*w4.w;
    }
#pragma unroll
    for (int e = 0; e < 16; e++) {
        float v = part[e];
#pragma unroll
        for (int off = 32; off > 0; off >>= 1) v += __shfl_down(v, off);
        if (lane == 0) g4[wid][e] = v;
    }
    __syncthreads();
    if (tid < 16) gsh[tid] = g4[0][tid] + g4[1][tid] + g4[2][tid] + g4[3][tid] + gb[tid];
    __syncthreads();
    if (tid == 0) {
        unsigned mask = 0;
        float vals[4]; int idxs[4];
#pragma unroll
        for (int k = 0; k < 4; k++) {
            float best = -1e30f; int bi = 0;
            for (int e = 0; e < 16; e++)
                if (!((mask >> e) & 1u) && gsh[e] > best) { best = gsh[e]; bi = e; }
            mask |= 1u << bi; vals[k] = best; idxs[k] = bi;
        }
        float m = vals[0], s = 0.f, w[4];
#pragma unroll
        for (int k = 0; k < 4; k++) { w[k] = __expf(vals[k] - m); s += w[k]; }
        float inv = 1.f / s;
#pragma unroll
        for (int k = 0; k < 4; k++) {
            int slot = atomicAdd(&cnt[idxs[k]], 1);
            pairs[idxs[k] * 2048 + slot] = t * 4 + k;
            pweight[t * 4 + k] = w[k] * inv;
        }
    }
}

// ---------------------------------------------------------------------------
// Kernel 2: GEMM1 (h = t @ W1^T + b1) + SwiGLU -> act (bf16).
// A: gathered bf16 token rows. B: fp32 weights, converted bf16 in staging.
// BM=128, BN=128 h-cols (even/odd-permuted), BK=64; 4 waves, 64x64 each.
// ---------------------------------------------------------------------------
__global__ __launch_bounds__(256, 1) void ffn1_kernel(
    const u16* __restrict__ t_ws, const float* __restrict__ w1,
    const float* __restrict__ b1, const int* __restrict__ cnt,
    const int* __restrict__ pairs, u16* __restrict__ act)
{
    const int e = blockIdx.z, mt = blockIdx.x, nt = blockIdx.y;
    const int cnt_e = cnt[e];
    if (mt * 128 >= cnt_e) return;
    const int tid = threadIdx.x;

    __shared__ u16 As[128 * 72];   // 64 K-cols + pad 8
    __shared__ u16 Bs[128 * 72];

    const float* w1e = w1 + (size_t)e * TWO_I * H_DIM;
    const int* plist = pairs + e * 2048;

    const u16* aptr[4]; const float* bptr[4]; int soff[4];
#pragma unroll
    for (int i = 0; i < 4; i++) {
        int c = tid + i * 256;
        int r = c >> 3, kc = c & 7;
        int gr = mt * 128 + r;
        int info = (gr < cnt_e) ? plist[gr] : plist[0];
        aptr[i] = t_ws + (size_t)(info >> 2) * H_DIM + kc * 8;
        soff[i] = r * 72 + kc * 8;
        // column permutation: tile pairs (even h-cols, odd h-cols)
        int t16 = r >> 4, l16 = r & 15;
        int hcol = nt * 128 + (t16 >> 1) * 32 + l16 * 2 + (t16 & 1);
        bptr[i] = w1e + (size_t)hcol * H_DIM + kc * 8;
    }

    const int lane = tid & 63, wid = tid >> 6;
    const int wm = wid >> 1, wn = wid & 1;
    const int l15 = lane & 15, quad = lane >> 4;

    f32x4 acc[4][4];
#pragma unroll
    for (int mi = 0; mi < 4; mi++)
#pragma unroll
        for (int ni = 0; ni < 4; ni++) acc[mi][ni] = (f32x4){0.f, 0.f, 0.f, 0.f};

    for (int ki = 0; ki < 16; ki++) {
        short8 ga[4]; float4 f0[4], f1[4];
#pragma unroll
        for (int i = 0; i < 4; i++) ga[i] = *(const short8*)(aptr[i] + ki * 64);
#pragma unroll
        for (int i = 0; i < 4; i++) {
            const float4* p = (const float4*)(bptr[i] + ki * 64);
            f0[i] = p[0]; f1[i] = p[1];
        }
        __syncthreads();
#pragma unroll
        for (int i = 0; i < 4; i++) *(short8*)(&As[soff[i]]) = ga[i];
#pragma unroll
        for (int i = 0; i < 4; i++) *(short8*)(&Bs[soff[i]]) = pack8(f0[i], f1[i]);
        __syncthreads();
#pragma unroll
        for (int ks = 0; ks < 2; ks++) {
            short8 af[4], bfr[4];
#pragma unroll
            for (int mi = 0; mi < 4; mi++)
                af[mi] = *(const short8*)(&As[(wm * 64 + mi * 16 + l15) * 72 + ks * 32 + quad * 8]);
#pragma unroll
            for (int ni = 0; ni < 4; ni++)
                bfr[ni] = *(const short8*)(&Bs[(wn * 64 + ni * 16 + l15) * 72 + ks * 32 + quad * 8]);
#pragma unroll
            for (int mi = 0; mi < 4; mi++)
#pragma unroll
                for (int ni = 0; ni < 4; ni++)
                    acc[mi][ni] = __builtin_amdgcn_mfma_f32_16x16x32_bf16(af[mi], bfr[ni], acc[mi][ni], 0, 0, 0);
        }
    }

    // epilogue: SwiGLU in-register (tile 2q=even h-cols, 2q+1=odd h-cols)
#pragma unroll
    for (int mi = 0; mi < 4; mi++) {
        int rloc = wm * 64 + mi * 16 + quad * 4;
        int rinfo[4]; bool rval[4];
#pragma unroll
        for (int rg = 0; rg < 4; rg++) {
            int gr = mt * 128 + rloc + rg;
            rval[rg] = gr < cnt_e;
            rinfo[rg] = rval[rg] ? plist[gr] : 0;
        }
#pragma unroll
        for (int qi = 0; qi < 2; qi++) {
            int actcol = nt * 64 + (wn * 2 + qi) * 16 + l15;
            float be = b1[e * TWO_I + 2 * actcol];
            float bo = b1[e * TWO_I + 2 * actcol + 1];
            f32x4 De = acc[mi][qi * 2], Do = acc[mi][qi * 2 + 1];
#pragma unroll
            for (int rg = 0; rg < 4; rg++) {
                if (!rval[rg]) continue;
                float he = De[rg] + be, ho = Do[rg] + bo;
                float glu = fminf(he, LIMIT);
                float lin = fminf(fmaxf(ho, -LIMIT), LIMIT);
                float a = glu * (1.f / (1.f + __expf(-ALPHA * glu))) * (lin + 1.f);
                act[(size_t)rinfo[rg] * I_DIM + actcol] = f2b(a);
            }
        }
    }
}

// ---------------------------------------------------------------------------
// Kernel 3: GEMM2 (y = act @ W2^T + b2) * softmax_weight -> atomicAdd accum.
// ---------------------------------------------------------------------------
__global__ __launch_bounds__(256, 1) void ffn2_kernel(
    const u16* __restrict__ act, const float* __restrict__ w2,
    const float* __restrict__ b2, const int* __restrict__ cnt,
    const int* __restrict__ pairs, const float* __restrict__ pweight,
    float* __restrict__ accum)
{
    const int e = blockIdx.z, mt = blockIdx.x, nt = blockIdx.y;
    const int cnt_e = cnt[e];
    if (mt * 128 >= cnt_e) return;
    const int tid = threadIdx.x;

    __shared__ u16 As[128 * 72];
    __shared__ u16 Bs[128 * 72];

    const float* w2e = w2 + (size_t)e * H_DIM * I_DIM;
    const int* plist = pairs + e * 2048;

    const u16* aptr[4]; const float* bptr[4]; int soff[4];
#pragma unroll
    for (int i = 0; i < 4; i++) {
        int c = tid + i * 256;
        int r = c >> 3, kc = c & 7;
        int gr = mt * 128 + r;
        int info = (gr < cnt_e) ? plist[gr] : plist[0];
        aptr[i] = act + (size_t)info * I_DIM + kc * 8;
        soff[i] = r * 72 + kc * 8;
        bptr[i] = w2e + (size_t)(nt * 128 + r) * I_DIM + kc * 8;
    }

    const int lane = tid & 63, wid = tid >> 6;
    const int wm = wid >> 1, wn = wid & 1;
    const int l15 = lane & 15, quad = lane >> 4;

    f32x4 acc[4][4];
#pragma unroll
    for (int mi = 0; mi < 4; mi++)
#pragma unroll
        for (int ni = 0; ni < 4; ni++) acc[mi][ni] = (f32x4){0.f, 0.f, 0.f, 0.f};

    for (int ki = 0; ki < 16; ki++) {
        short8 ga[4]; float4 f0[4], f1[4];
#pragma unroll
        for (int i = 0; i < 4; i++) ga[i] = *(const short8*)(aptr[i] + ki * 64);
#pragma unroll
        for (int i = 0; i < 4; i++) {
            const float4* p = (const float4*)(bptr[i] + ki * 64);
            f0[i] = p[0]; f1[i] = p[1];
        }
        __syncthreads();
#pragma unroll
        for (int i = 0; i < 4; i++) *(short8*)(&As[soff[i]]) = ga[i];
#pragma unroll
        for (int i = 0; i < 4; i++) *(short8*)(&Bs[soff[i]]) = pack8(f0[i], f1[i]);
        __syncthreads();
#pragma unroll
        for (int ks = 0; ks < 2; ks++) {
            short8 af[4], bfr[4];
#pragma unroll
            for (int mi = 0; mi < 4; mi++)
                af[mi] = *(const short8*)(&As[(wm * 64 + mi * 16 + l15) * 72 + ks * 32 + quad * 8]);
#pragma unroll
            for (int ni = 0; ni < 4; ni++)
                bfr[ni] = *(const short8*)(&Bs[(wn * 64 + ni * 16 + l15) * 72 + ks * 32 + quad * 8]);
#pragma unroll
            for (int mi = 0; mi < 4; mi++)
#pragma unroll
                for (int ni = 0; ni < 4; ni++)
                    acc[mi][ni] = __builtin_amdgcn_mfma_f32_16x16x32_bf16(af[mi], bfr[ni], acc[mi][ni], 0, 0, 0);
        }
    }

#pragma unroll
    for (int mi = 0; mi < 4; mi++) {
        int rloc = wm * 64 + mi * 16 + quad * 4;
        int rinfo[4]; bool rval[4]; float wp[4];
#pragma unroll
        for (int rg = 0; rg < 4; rg++) {
            int gr = mt * 128 + rloc + rg;
            rval[rg] = gr < cnt_e;
            rinfo[rg] = rval[rg] ? plist[gr] : 0;
            wp[rg] = rval[rg] ? pweight[rinfo[rg]] : 0.f;
        }
#pragma unroll
        for (int ni = 0; ni < 4; ni++) {
            int hc = nt * 128 + wn * 64 + ni * 16 + l15;
            float bv = b2[e * H_DIM + hc];
#pragma unroll
            for (int rg = 0; rg < 4; rg++) {
                if (!rval[rg]) continue;
                float val = (acc[mi][ni][rg] + bv) * wp[rg];
                atomicAdd(&accum[(size_t)(rinfo[rg] >> 2) * H_DIM + hc], val);
            }
        }
    }
}

// ---------------------------------------------------------------------------
// Kernel 4: out_fp32 = x_fp32 + accum_fp32.   (output dtype is FLOAT32 —
// the reference returns fp32; the "(bf16, ref=np)" label is only the
// threshold floor. 2048 blocks x 256 thr x 1 float4 = 2M floats exactly.)
// ---------------------------------------------------------------------------
__global__ __launch_bounds__(256) void finalize_kernel(
    const float* __restrict__ x, const float* __restrict__ accum,
    float* __restrict__ out)
{
    int idx = blockIdx.x * 256 + threadIdx.x;      // one float4 per thread
    float4 xv = ((const float4*)x)[idx];
    float4 av = ((const float4*)accum)[idx];
    float4 o;
    o.x = xv.x + av.x; o.y = xv.y + av.y;
    o.z = xv.z + av.z; o.w = xv.w + av.w;
    ((float4*)out)[idx] = o;
}

extern "C" void kernel_launch(void* const* d_in, const int* in_sizes, int n_in,
                              void* d_out, int out_size, void* d_ws, size_t ws_size,
                              hipStream_t stream)
{
    const float* x      = (const float*)d_in[0];
    const float* nscale = (const float*)d_in[1];
    const float* gate_w = (const float*)d_in[2];
    const float* gate_b = (const float*)d_in[3];
    const float* mlp1_w = (const float*)d_in[4];
    const float* mlp1_b = (const float*)d_in[5];
    const float* mlp2_w = (const float*)d_in[6];
    const float* mlp2_b = (const float*)d_in[7];
    float* out = (float*)d_out;

    char* ws = (char*)d_ws;
    u16*   t_ws  = (u16*)(ws);                          // 4 MiB bf16 normalized tokens
    u16*   act   = (u16*)(ws + (4u << 20));             // 16 MiB bf16 act[pair][I]
    float* accum = (float*)(ws + (20u << 20));          // 8 MiB fp32 accumulator [T][H]
    int*   cnt   = (int*)(ws + (28u << 20));            // E counters
    int*   pairs = (int*)(ws + (28u << 20) + 1024);     // [E][2048]
    float* pw    = (float*)(ws + (28u << 20) + 1024 + E_NUM * 2048 * 4); // [T*4]

    hipMemsetAsync(cnt, 0, E_NUM * sizeof(int), stream);
    hipMemsetAsync(accum, 0, (size_t)T_TOK * H_DIM * sizeof(float), stream);

    prep_kernel<<<T_TOK, 256, 0, stream>>>(x, nscale, gate_w, gate_b, t_ws, cnt, pairs, pw);
    ffn1_kernel<<<dim3(16, 16, E_NUM), 256, 0, stream>>>(t_ws, mlp1_w, mlp1_b, cnt, pairs, act);
    ffn2_kernel<<<dim3(16, 8, E_NUM), 256, 0, stream>>>(act, mlp2_w, mlp2_b, cnt, pairs, pw, accum);
    finalize_kernel<<<T_TOK, 256, 0, stream>>>(x, accum, out);
}

// Round 5
// 525.216 us; speedup vs baseline: 1.5221x; 1.5221x over previous
//
#include <hip/hip_runtime.h>
#include <hip/hip_bf16.h>
#include <stdint.h>

typedef unsigned short u16;
typedef __attribute__((ext_vector_type(8))) short short8;
typedef __attribute__((ext_vector_type(4))) float f32x4;

#define T_TOK 2048
#define H_DIM 1024
#define E_NUM 16
#define TWO_I 2048
#define I_DIM 1024
#define ALPHA 1.702f
#define LIMIT 7.0f

__device__ __forceinline__ u16 f2b(float f) {
    uint32_t x = __builtin_bit_cast(uint32_t, f);
    uint32_t r = x + 0x7fffu + ((x >> 16) & 1u);
    return (u16)(r >> 16);
}
__device__ __forceinline__ short8 pack8(float4 a, float4 b) {
    short8 r;
    r[0] = (short)f2b(a.x); r[1] = (short)f2b(a.y);
    r[2] = (short)f2b(a.z); r[3] = (short)f2b(a.w);
    r[4] = (short)f2b(b.x); r[5] = (short)f2b(b.y);
    r[6] = (short)f2b(b.z); r[7] = (short)f2b(b.w);
    return r;
}

// B-fragment loader: bf16 (pre-converted) or fp32 (fallback, packs at store)
template<typename BT> struct BFrag;
template<> struct BFrag<u16> {
    short8 v;
    __device__ __forceinline__ void load(const u16* p) { v = *(const short8*)p; }
    __device__ __forceinline__ short8 get() const { return v; }
};
template<> struct BFrag<float> {
    float4 a, b;
    __device__ __forceinline__ void load(const float* p) {
        const float4* q = (const float4*)p; a = q[0]; b = q[1];
    }
    __device__ __forceinline__ short8 get() const { return pack8(a, b); }
};

// ---------------------------------------------------------------------------
// Kernel 0: fp32 -> bf16 streaming convert (grid-stride, float4 per thread)
// ---------------------------------------------------------------------------
__global__ __launch_bounds__(256) void cvt_kernel(
    const float* __restrict__ in, u16* __restrict__ out, int n4)
{
    int i = blockIdx.x * 256 + threadIdx.x;
    int stride = gridDim.x * 256;
    for (; i < n4; i += stride) {
        float4 v = ((const float4*)in)[i];
        uint32_t lo = (uint32_t)f2b(v.x) | ((uint32_t)f2b(v.y) << 16);
        uint32_t hi = (uint32_t)f2b(v.z) | ((uint32_t)f2b(v.w) << 16);
        uint2 p; p.x = lo; p.y = hi;
        ((uint2*)out)[i] = p;
    }
}

// ---------------------------------------------------------------------------
// Kernel 1: RMSNorm + gate + top-4 + softmax + expert scatter. 1 block/token.
// ---------------------------------------------------------------------------
__global__ __launch_bounds__(256) void prep_kernel(
    const float* __restrict__ x, const float* __restrict__ scale,
    const float* __restrict__ gw, const float* __restrict__ gb,
    u16* __restrict__ t_out, int* __restrict__ cnt,
    int* __restrict__ pairs, float* __restrict__ pweight)
{
    const int t = blockIdx.x, tid = threadIdx.x;
    const int lane = tid & 63, wid = tid >> 6;
    __shared__ float red[4];
    __shared__ float g4[4][16];
    __shared__ float gsh[16];
    __shared__ float rstd_sh;

    const float4 xv = ((const float4*)(x + (size_t)t * H_DIM))[tid];
    float ss = xv.x*xv.x + xv.y*xv.y + xv.z*xv.z + xv.w*xv.w;
#pragma unroll
    for (int off = 32; off > 0; off >>= 1) ss += __shfl_down(ss, off);
    if (lane == 0) red[wid] = ss;
    __syncthreads();
    if (tid == 0) rstd_sh = rsqrtf((red[0]+red[1]+red[2]+red[3]) * (1.f/1024.f) + 1e-5f);
    __syncthreads();
    const float rstd = rstd_sh;
    const float4 sc = ((const float4*)scale)[tid];
    float4 tv;
    tv.x = xv.x * rstd * sc.x; tv.y = xv.y * rstd * sc.y;
    tv.z = xv.z * rstd * sc.z; tv.w = xv.w * rstd * sc.w;
    {
        uint32_t lo = (uint32_t)f2b(tv.x) | ((uint32_t)f2b(tv.y) << 16);
        uint32_t hi = (uint32_t)f2b(tv.z) | ((uint32_t)f2b(tv.w) << 16);
        uint2 p; p.x = lo; p.y = hi;
        *(uint2*)(t_out + (size_t)t * H_DIM + tid * 4) = p;
    }
    float part[16];
#pragma unroll
    for (int e = 0; e < 16; e++) {
        const float4 w4 = ((const float4*)(gw + (size_t)e * H_DIM))[tid];
        part[e] = tv.x*w4.x + tv.y*w4.y + tv.z*w4.z + tv.w*w4.w;
    }
#pragma unroll
    for (int e = 0; e < 16; e++) {
        float v = part[e];
#pragma unroll
        for (int off = 32; off > 0; off >>= 1) v += __shfl_down(v, off);
        if (lane == 0) g4[wid][e] = v;
    }
    __syncthreads();
    if (tid < 16) gsh[tid] = g4[0][tid] + g4[1][tid] + g4[2][tid] + g4[3][tid] + gb[tid];
    __syncthreads();
    if (tid == 0) {
        unsigned mask = 0;
        float vals[4]; int idxs[4];
#pragma unroll
        for (int k = 0; k < 4; k++) {
            float best = -1e30f; int bi = 0;
            for (int e = 0; e < 16; e++)
                if (!((mask >> e) & 1u) && gsh[e] > best) { best = gsh[e]; bi = e; }
            mask |= 1u << bi; vals[k] = best; idxs[k] = bi;
        }
        float m = vals[0], s = 0.f, w[4];
#pragma unroll
        for (int k = 0; k < 4; k++) { w[k] = __expf(vals[k] - m); s += w[k]; }
        float inv = 1.f / s;
#pragma unroll
        for (int k = 0; k < 4; k++) {
            int slot = atomicAdd(&cnt[idxs[k]], 1);
            pairs[idxs[k] * 2048 + slot] = t * 4 + k;
            pweight[t * 4 + k] = w[k] * inv;
        }
    }
}

// ---------------------------------------------------------------------------
// Kernel 2: GEMM1 (h = t @ W1^T + b1) + SwiGLU -> act (bf16).
// Software-pipelined: prefetch k-tile ki+1 into regs during MFMA of ki.
// grid: x=nt (always live), y=mt (early-exit), z=e.
// ---------------------------------------------------------------------------
template<typename BT>
__global__ __launch_bounds__(256, 1) void ffn1_kernel(
    const u16* __restrict__ t_ws, const BT* __restrict__ w1,
    const float* __restrict__ b1, const int* __restrict__ cnt,
    const int* __restrict__ pairs, u16* __restrict__ act)
{
    const int e = blockIdx.z, nt = blockIdx.x, mt = blockIdx.y;
    const int cnt_e = cnt[e];
    if (mt * 128 >= cnt_e) return;
    const int tid = threadIdx.x;

    __shared__ u16 As[128 * 72];   // 64 K-cols + pad 8
    __shared__ u16 Bs[128 * 72];

    const BT* w1e = w1 + (size_t)e * TWO_I * H_DIM;
    const int* plist = pairs + e * 2048;

    const u16* aptr[4]; const BT* bptr[4]; int soff[4];
#pragma unroll
    for (int i = 0; i < 4; i++) {
        int c = tid + i * 256;
        int r = c >> 3, kc = c & 7;
        int gr = mt * 128 + r;
        int info = (gr < cnt_e) ? plist[gr] : plist[0];
        aptr[i] = t_ws + (size_t)(info >> 2) * H_DIM + kc * 8;
        soff[i] = r * 72 + kc * 8;
        // column permutation: tile pairs (even h-cols, odd h-cols)
        int t16 = r >> 4, l16 = r & 15;
        int hcol = nt * 128 + (t16 >> 1) * 32 + l16 * 2 + (t16 & 1);
        bptr[i] = w1e + (size_t)hcol * H_DIM + kc * 8;
    }

    const int lane = tid & 63, wid = tid >> 6;
    const int wm = wid >> 1, wn = wid & 1;
    const int l15 = lane & 15, quad = lane >> 4;

    f32x4 acc[4][4];
#pragma unroll
    for (int mi = 0; mi < 4; mi++)
#pragma unroll
        for (int ni = 0; ni < 4; ni++) acc[mi][ni] = (f32x4){0.f, 0.f, 0.f, 0.f};

    short8 ga[4]; BFrag<BT> gb[4];
#pragma unroll
    for (int i = 0; i < 4; i++) ga[i] = *(const short8*)(aptr[i]);
#pragma unroll
    for (int i = 0; i < 4; i++) gb[i].load(bptr[i]);

    for (int ki = 0; ki < 16; ki++) {
        __syncthreads();                       // prior iter's readers done
#pragma unroll
        for (int i = 0; i < 4; i++) *(short8*)(&As[soff[i]]) = ga[i];
#pragma unroll
        for (int i = 0; i < 4; i++) *(short8*)(&Bs[soff[i]]) = gb[i].get();
        __syncthreads();
        if (ki < 15) {                         // prefetch under MFMA section
#pragma unroll
            for (int i = 0; i < 4; i++) ga[i] = *(const short8*)(aptr[i] + (ki+1) * 64);
#pragma unroll
            for (int i = 0; i < 4; i++) gb[i].load(bptr[i] + (ki+1) * 64);
        }
#pragma unroll
        for (int ks = 0; ks < 2; ks++) {
            short8 af[4], bfr[4];
#pragma unroll
            for (int mi = 0; mi < 4; mi++)
                af[mi] = *(const short8*)(&As[(wm * 64 + mi * 16 + l15) * 72 + ks * 32 + quad * 8]);
#pragma unroll
            for (int ni = 0; ni < 4; ni++)
                bfr[ni] = *(const short8*)(&Bs[(wn * 64 + ni * 16 + l15) * 72 + ks * 32 + quad * 8]);
#pragma unroll
            for (int mi = 0; mi < 4; mi++)
#pragma unroll
                for (int ni = 0; ni < 4; ni++)
                    acc[mi][ni] = __builtin_amdgcn_mfma_f32_16x16x32_bf16(af[mi], bfr[ni], acc[mi][ni], 0, 0, 0);
        }
    }

    // epilogue: SwiGLU in-register (tile 2q=even h-cols, 2q+1=odd h-cols)
#pragma unroll
    for (int mi = 0; mi < 4; mi++) {
        int rloc = wm * 64 + mi * 16 + quad * 4;
        int rinfo[4]; bool rval[4];
#pragma unroll
        for (int rg = 0; rg < 4; rg++) {
            int gr = mt * 128 + rloc + rg;
            rval[rg] = gr < cnt_e;
            rinfo[rg] = rval[rg] ? plist[gr] : 0;
        }
#pragma unroll
        for (int qi = 0; qi < 2; qi++) {
            int actcol = nt * 64 + (wn * 2 + qi) * 16 + l15;
            float be = b1[e * TWO_I + 2 * actcol];
            float bo = b1[e * TWO_I + 2 * actcol + 1];
            f32x4 De = acc[mi][qi * 2], Do = acc[mi][qi * 2 + 1];
#pragma unroll
            for (int rg = 0; rg < 4; rg++) {
                if (!rval[rg]) continue;
                float he = De[rg] + be, ho = Do[rg] + bo;
                float glu = fminf(he, LIMIT);
                float lin = fminf(fmaxf(ho, -LIMIT), LIMIT);
                float a = glu * (1.f / (1.f + __expf(-ALPHA * glu))) * (lin + 1.f);
                act[(size_t)rinfo[rg] * I_DIM + actcol] = f2b(a);
            }
        }
    }
}

// ---------------------------------------------------------------------------
// Kernel 3: GEMM2 (y = act @ W2^T + b2) * softmax_weight -> atomicAdd accum.
// Same pipelined structure. grid: x=nt(8), y=mt(16), z=e.
// ---------------------------------------------------------------------------
template<typename BT>
__global__ __launch_bounds__(256, 1) void ffn2_kernel(
    const u16* __restrict__ act, const BT* __restrict__ w2,
    const float* __restrict__ b2, const int* __restrict__ cnt,
    const int* __restrict__ pairs, const float* __restrict__ pweight,
    float* __restrict__ accum)
{
    const int e = blockIdx.z, nt = blockIdx.x, mt = blockIdx.y;
    const int cnt_e = cnt[e];
    if (mt * 128 >= cnt_e) return;
    const int tid = threadIdx.x;

    __shared__ u16 As[128 * 72];
    __shared__ u16 Bs[128 * 72];

    const BT* w2e = w2 + (size_t)e * H_DIM * I_DIM;
    const int* plist = pairs + e * 2048;

    const u16* aptr[4]; const BT* bptr[4]; int soff[4];
#pragma unroll
    for (int i = 0; i < 4; i++) {
        int c = tid + i * 256;
        int r = c >> 3, kc = c & 7;
        int gr = mt * 128 + r;
        int info = (gr < cnt_e) ? plist[gr] : plist[0];
        aptr[i] = act + (size_t)info * I_DIM + kc * 8;
        soff[i] = r * 72 + kc * 8;
        bptr[i] = w2e + (size_t)(nt * 128 + r) * I_DIM + kc * 8;
    }

    const int lane = tid & 63, wid = tid >> 6;
    const int wm = wid >> 1, wn = wid & 1;
    const int l15 = lane & 15, quad = lane >> 4;

    f32x4 acc[4][4];
#pragma unroll
    for (int mi = 0; mi < 4; mi++)
#pragma unroll
        for (int ni = 0; ni < 4; ni++) acc[mi][ni] = (f32x4){0.f, 0.f, 0.f, 0.f};

    short8 ga[4]; BFrag<BT> gb[4];
#pragma unroll
    for (int i = 0; i < 4; i++) ga[i] = *(const short8*)(aptr[i]);
#pragma unroll
    for (int i = 0; i < 4; i++) gb[i].load(bptr[i]);

    for (int ki = 0; ki < 16; ki++) {
        __syncthreads();
#pragma unroll
        for (int i = 0; i < 4; i++) *(short8*)(&As[soff[i]]) = ga[i];
#pragma unroll
        for (int i = 0; i < 4; i++) *(short8*)(&Bs[soff[i]]) = gb[i].get();
        __syncthreads();
        if (ki < 15) {
#pragma unroll
            for (int i = 0; i < 4; i++) ga[i] = *(const short8*)(aptr[i] + (ki+1) * 64);
#pragma unroll
            for (int i = 0; i < 4; i++) gb[i].load(bptr[i] + (ki+1) * 64);
        }
#pragma unroll
        for (int ks = 0; ks < 2; ks++) {
            short8 af[4], bfr[4];
#pragma unroll
            for (int mi = 0; mi < 4; mi++)
                af[mi] = *(const short8*)(&As[(wm * 64 + mi * 16 + l15) * 72 + ks * 32 + quad * 8]);
#pragma unroll
            for (int ni = 0; ni < 4; ni++)
                bfr[ni] = *(const short8*)(&Bs[(wn * 64 + ni * 16 + l15) * 72 + ks * 32 + quad * 8]);
#pragma unroll
            for (int mi = 0; mi < 4; mi++)
#pragma unroll
                for (int ni = 0; ni < 4; ni++)
                    acc[mi][ni] = __builtin_amdgcn_mfma_f32_16x16x32_bf16(af[mi], bfr[ni], acc[mi][ni], 0, 0, 0);
        }
    }

#pragma unroll
    for (int mi = 0; mi < 4; mi++) {
        int rloc = wm * 64 + mi * 16 + quad * 4;
        int rinfo[4]; bool rval[4]; float wp[4];
#pragma unroll
        for (int rg = 0; rg < 4; rg++) {
            int gr = mt * 128 + rloc + rg;
            rval[rg] = gr < cnt_e;
            rinfo[rg] = rval[rg] ? plist[gr] : 0;
            wp[rg] = rval[rg] ? pweight[rinfo[rg]] : 0.f;
        }
#pragma unroll
        for (int ni = 0; ni < 4; ni++) {
            int hc = nt * 128 + wn * 64 + ni * 16 + l15;
            float bv = b2[e * H_DIM + hc];
#pragma unroll
            for (int rg = 0; rg < 4; rg++) {
                if (!rval[rg]) continue;
                float val = (acc[mi][ni][rg] + bv) * wp[rg];
                atomicAdd(&accum[(size_t)(rinfo[rg] >> 2) * H_DIM + hc], val);
            }
        }
    }
}

// ---------------------------------------------------------------------------
// Kernel 4: out_fp32 = x_fp32 + accum_fp32 (2048 x 256 x float4 = 2M exactly)
// ---------------------------------------------------------------------------
__global__ __launch_bounds__(256) void finalize_kernel(
    const float* __restrict__ x, const float* __restrict__ accum,
    float* __restrict__ out)
{
    int idx = blockIdx.x * 256 + threadIdx.x;
    float4 xv = ((const float4*)x)[idx];
    float4 av = ((const float4*)accum)[idx];
    float4 o;
    o.x = xv.x + av.x; o.y = xv.y + av.y;
    o.z = xv.z + av.z; o.w = xv.w + av.w;
    ((float4*)out)[idx] = o;
}

extern "C" void kernel_launch(void* const* d_in, const int* in_sizes, int n_in,
                              void* d_out, int out_size, void* d_ws, size_t ws_size,
                              hipStream_t stream)
{
    const float* x      = (const float*)d_in[0];
    const float* nscale = (const float*)d_in[1];
    const float* gate_w = (const float*)d_in[2];
    const float* gate_b = (const float*)d_in[3];
    const float* mlp1_w = (const float*)d_in[4];
    const float* mlp1_b = (const float*)d_in[5];
    const float* mlp2_w = (const float*)d_in[6];
    const float* mlp2_b = (const float*)d_in[7];
    float* out = (float*)d_out;

    char* ws = (char*)d_ws;
    u16*   t_ws  = (u16*)(ws);                          //  0M: 4 MiB bf16 tokens
    u16*   act   = (u16*)(ws + (4ull << 20));           //  4M: 16 MiB bf16 act
    float* accum = (float*)(ws + (20ull << 20));        // 20M: 8 MiB fp32 accum
    int*   cnt   = (int*)(ws + (28ull << 20));          // 28M: counters + lists
    int*   pairs = (int*)(ws + (28ull << 20) + 1024);
    float* pw    = (float*)(ws + (28ull << 20) + 1024 + E_NUM * 2048 * 4);
    u16*   w1b   = (u16*)(ws + (32ull << 20));          // 32M: 64 MiB bf16 W1
    u16*   w2b   = (u16*)(ws + (96ull << 20));          // 96M: 32 MiB bf16 W2

    const bool big = ws_size >= (128ull << 20);

    hipMemsetAsync(cnt, 0, E_NUM * sizeof(int), stream);
    hipMemsetAsync(accum, 0, (size_t)T_TOK * H_DIM * sizeof(float), stream);

    if (big) {
        cvt_kernel<<<2048, 256, 0, stream>>>(mlp1_w, w1b, E_NUM * TWO_I * H_DIM / 4);
        cvt_kernel<<<2048, 256, 0, stream>>>(mlp2_w, w2b, E_NUM * H_DIM * I_DIM / 4);
    }
    prep_kernel<<<T_TOK, 256, 0, stream>>>(x, nscale, gate_w, gate_b, t_ws, cnt, pairs, pw);
    if (big) {
        ffn1_kernel<u16><<<dim3(16, 16, E_NUM), 256, 0, stream>>>(t_ws, w1b, mlp1_b, cnt, pairs, act);
        ffn2_kernel<u16><<<dim3(8, 16, E_NUM), 256, 0, stream>>>(act, w2b, mlp2_b, cnt, pairs, pw, accum);
    } else {
        ffn1_kernel<float><<<dim3(16, 16, E_NUM), 256, 0, stream>>>(t_ws, mlp1_w, mlp1_b, cnt, pairs, act);
        ffn2_kernel<float><<<dim3(8, 16, E_NUM), 256, 0, stream>>>(act, mlp2_w, mlp2_b, cnt, pairs, pw, accum);
    }
    finalize_kernel<<<T_TOK, 256, 0, stream>>>(x, accum, out);
}